// Round 1
// baseline (252.381 us; speedup 1.0000x reference)
//
#include <hip/hip_runtime.h>
#include <hip/hip_bf16.h>

#define N_NODES 140000
#define N_EDGES 2240000
#define NFEAT 128
#define NHID 128
#define N_FRAMES 14
#define NODES_PER_FRAME 10000
#define CAP 352            // int2 LDS slots per wave (7 frames padded to x8)

#define N_TILES 8750       // N_NODES / 16, exact
#define GEMM_GRID 1024     // 4 blocks/CU by LDS (34.8 KB) -> fully resident
#define EDGE_BLOCKS ((N_EDGES + 255) / 256)
#define WT_STRIDE 136

typedef __attribute__((ext_vector_type(8))) short frag_b16;
typedef __attribute__((ext_vector_type(4))) int frag_i4;
typedef __attribute__((ext_vector_type(4))) float f32x4;

__device__ __forceinline__ unsigned short f2bf(float f) {
    union { float f; unsigned int u; } v; v.f = f;
    unsigned int r = v.u + 0x7fffu + ((v.u >> 16) & 1u);   // RNE
    return (unsigned short)(r >> 16);
}
__device__ __forceinline__ int pk_bf16(float a, float b) {
    union { __hip_bfloat162 h; int i; } u;
    u.h = __float22bfloat162_rn(make_float2(a, b));        // v_cvt_pk_bf16_f32
    return u.i;
}

// ---------------------------------------------------------------------------
// Fused prep + GEMM.
//  blocks [0, GEMM_GRID):   support = x @ W with int8 row-quant epilogue.
//    - W (f32, 64 KB, L2-resident) converted bf16 + transposed into LDS
//      ONCE per block, then grid-stride over 16-row tiles (~2.14 tiles/wave)
//      with register-double-buffered x prefetch (next tile's loads hide
//      under current tile's MFMA + epilogue).
//  blocks [GEMM_GRID, ...): CSR row_ptr from sorted COO rows (old prep).
// ---------------------------------------------------------------------------
__global__ __launch_bounds__(256, 4) void gemm_prep_kernel(
        const float* __restrict__ x, const float* __restrict__ W,
        const int* __restrict__ edge_row, int* __restrict__ row_ptr,
        unsigned char* __restrict__ supQ, float* __restrict__ scales) {

    if (blockIdx.x >= GEMM_GRID) {
        int e = (blockIdx.x - GEMM_GRID) * 256 + threadIdx.x;
        if (e < N_EDGES) {
            int r = edge_row[e];
            int prev = (e == 0) ? -1 : edge_row[e - 1];
            for (int q = prev + 1; q <= r; ++q) row_ptr[q] = e;
            if (e == N_EDGES - 1) {
                for (int q = r + 1; q <= N_NODES; ++q) row_ptr[q] = N_EDGES;
            }
        }
        return;
    }

    __shared__ unsigned short wt_lds[128 * WT_STRIDE];

    const int wave = threadIdx.x >> 6;
    const int lane = threadIdx.x & 63;
    const int m = lane & 15;
    const int q = lane >> 4;

    // --- issue first tile's x loads before W staging (all in flight together)
    int tile = blockIdx.x * 4 + wave;
    float4 pf[8];
    {
        const float* xr = x + (long)(tile * 16 + m) * 128 + q * 8;
#pragma unroll
        for (int ks = 0; ks < 4; ++ks) {
            pf[2 * ks]     = *(const float4*)(xr + ks * 32);
            pf[2 * ks + 1] = *(const float4*)(xr + ks * 32 + 4);
        }
    }

    // --- stage W[k][n] (f32) -> wt_lds[n][k] (bf16, transposed), once/block
    for (int idx = threadIdx.x; idx < 4096; idx += 256) {
        float4 wv = ((const float4*)W)[idx];
        int k = idx >> 5;              // row of W
        int n = (idx & 31) << 2;       // col of W
        wt_lds[(n + 0) * WT_STRIDE + k] = f2bf(wv.x);
        wt_lds[(n + 1) * WT_STRIDE + k] = f2bf(wv.y);
        wt_lds[(n + 2) * WT_STRIDE + k] = f2bf(wv.z);
        wt_lds[(n + 3) * WT_STRIDE + k] = f2bf(wv.w);
    }
    __syncthreads();

    for (;;) {
        // convert current tile's x to bf16 fragments
        frag_b16 xa[4];
#pragma unroll
        for (int ks = 0; ks < 4; ++ks) {
            union { frag_b16 f; frag_i4 i; } u;
            u.i[0] = pk_bf16(pf[2 * ks].x, pf[2 * ks].y);
            u.i[1] = pk_bf16(pf[2 * ks].z, pf[2 * ks].w);
            u.i[2] = pk_bf16(pf[2 * ks + 1].x, pf[2 * ks + 1].y);
            u.i[3] = pk_bf16(pf[2 * ks + 1].z, pf[2 * ks + 1].w);
            xa[ks] = u.f;
        }

        // prefetch next tile's x (hides under MFMA + epilogue)
        const int next = tile + GEMM_GRID * 4;
        const bool more = next < N_TILES;
        if (more) {
            const float* xr = x + (long)(next * 16 + m) * 128 + q * 8;
#pragma unroll
            for (int ks = 0; ks < 4; ++ks) {
                pf[2 * ks]     = *(const float4*)(xr + ks * 32);
                pf[2 * ks + 1] = *(const float4*)(xr + ks * 32 + 4);
            }
        }

        f32x4 acc[8];
#pragma unroll
        for (int t = 0; t < 8; ++t) acc[t] = (f32x4){0.f, 0.f, 0.f, 0.f};

#pragma unroll
        for (int t = 0; t < 8; ++t) {
            const unsigned short* bp = &wt_lds[(t * 16 + m) * WT_STRIDE + q * 8];
#pragma unroll
            for (int ks = 0; ks < 4; ++ks) {
                frag_b16 wfrag = *(const frag_b16*)(bp + ks * 32);
                acc[t] = __builtin_amdgcn_mfma_f32_16x16x32_bf16(wfrag, xa[ks], acc[t], 0, 0, 0);
            }
        }

        // --- int8 row quantization epilogue ---
        float amax = 0.f;
#pragma unroll
        for (int t = 0; t < 8; ++t)
#pragma unroll
            for (int r = 0; r < 4; ++r) amax = fmaxf(amax, fabsf(acc[t][r]));
        amax = fmaxf(amax, __shfl_xor(amax, 16));
        amax = fmaxf(amax, __shfl_xor(amax, 32));
        float rinv = amax > 0.f ? 127.f / amax : 0.f;

        long node = (long)tile * 16 + m;
        if (q == 0) scales[node] = amax * (1.f / 127.f);
        unsigned char* srow = supQ + node * 128;
#pragma unroll
        for (int t = 0; t < 8; ++t) {
            unsigned u0 = (unsigned)(rintf(acc[t][0] * rinv) + 128.f);
            unsigned u1 = (unsigned)(rintf(acc[t][1] * rinv) + 128.f);
            unsigned u2 = (unsigned)(rintf(acc[t][2] * rinv) + 128.f);
            unsigned u3 = (unsigned)(rintf(acc[t][3] * rinv) + 128.f);
            *(unsigned*)(srow + t * 16 + q * 4) = u0 | (u1 << 8) | (u2 << 16) | (u3 << 24);
        }

        if (!more) break;
        tile = next;
    }
}

// ---------------------------------------------------------------------------
// Fused aggregation v3 (unchanged from verified 67 us version).
// Block = 128 thr = 2 waves = 1 output node. Wave w: frames [7w, 7w+6].
// ---------------------------------------------------------------------------
__global__ __launch_bounds__(128) void agg_kernel(
        const unsigned char* __restrict__ supQ, const float* __restrict__ scales,
        const float* __restrict__ b,
        const float* __restrict__ edge_val, const int* __restrict__ edge_col,
        const int* __restrict__ row_ptr, float* __restrict__ out) {
    __shared__ int    segStart[2][8];
    __shared__ int    segLen[2][8];
    __shared__ int    segOff[2][8];
    __shared__ int2   eBuf[2][CAP];
    __shared__ float4 xch[2][32];

    const int i = blockIdx.x;
    const int lane = threadIdx.x & 63;
    const int w = threadIdx.x >> 6;
    const int eh = lane >> 5;                          // which edge of a pair
    const int f4 = lane & 31;                          // feature quad
    const unsigned f4x4 = (unsigned)f4 * 4u;

    // --- CSR ranges in lanes 0..6; padded-to-8 exclusive scan ---
    int a = 0, len = 0;
    if (lane < 7) {
        int n = (w * 7 + lane) * NODES_PER_FRAME + i;
        a = row_ptr[n];
        len = row_ptr[n + 1] - a;
    }
    int len8 = (len + 7) & ~7;
    int off = 0;
#pragma unroll
    for (int f2 = 0; f2 < 7; ++f2) {
        int L2 = __shfl(len8, f2);
        if (f2 < lane) off += L2;
    }
    if (lane < 7) { segStart[w][lane] = a; segLen[w][lane] = len; segOff[w][lane] = off; }
    if (lane == 6) segOff[w][7] = off + len8;
    __syncthreads();

    const bool fit = segOff[w][7] <= CAP;              // wave-uniform

    // --- stage (col, val'=val*scale[col]) into LDS, zero-padded per frame ---
    if (fit) {
#pragma unroll 1
        for (int f = 0; f < 7; ++f) {
            int g = segStart[w][f], s = segOff[w][f], L = segLen[w][f];
            int L8 = (L + 7) & ~7;
            for (int j = lane; j < L8; j += 64) {
                int2 v = make_int2(0, 0);
                if (j < L) {
                    int c = edge_col[g + j];
                    v.x = c;
                    v.y = __float_as_int(edge_val[g + j] * scales[c]);
                }
                eBuf[w][s + j] = v;
            }
        }
    }
    __syncthreads();

    const float4 bb = *(const float4*)&b[f4 * 4];
    float4 mx = make_float4(0.f, 0.f, 0.f, 0.f);       // relu => max >= 0

    if (fit) {
#pragma unroll 1
        for (int f = 0; f < 7; ++f) {
            int s = segOff[w][f];
            int e8 = s + ((segLen[w][f] + 7) & ~7);
            float a0 = 0.f, a1 = 0.f, a2 = 0.f, a3 = 0.f, svf = 0.f;
            for (int j = s; j < e8; j += 8) {
                int2 ed[4];
#pragma unroll
                for (int p = 0; p < 4; ++p) ed[p] = eBuf[w][j + 2 * p + eh];
                unsigned q4[4];
#pragma unroll
                for (int p = 0; p < 4; ++p)
                    q4[p] = *(const unsigned*)(supQ + (((unsigned)ed[p].x) << 7) + f4x4);
#pragma unroll
                for (int p = 0; p < 4; ++p) {
                    float vp = __int_as_float(ed[p].y);
                    a0 = fmaf(vp, (float)( q4[p]        & 0xffu), a0);
                    a1 = fmaf(vp, (float)((q4[p] >> 8)  & 0xffu), a1);
                    a2 = fmaf(vp, (float)((q4[p] >> 16) & 0xffu), a2);
                    a3 = fmaf(vp, (float)( q4[p] >> 24        ), a3);
                    svf += vp;
                }
            }
            a0 += __shfl_xor(a0, 32); a1 += __shfl_xor(a1, 32);
            a2 += __shfl_xor(a2, 32); a3 += __shfl_xor(a3, 32);
            svf += __shfl_xor(svf, 32);
            float h0 = fmaf(-128.f, svf, a0) + bb.x;
            float h1 = fmaf(-128.f, svf, a1) + bb.y;
            float h2 = fmaf(-128.f, svf, a2) + bb.z;
            float h3 = fmaf(-128.f, svf, a3) + bb.w;
            mx.x = fmaxf(mx.x, fmaxf(h0, 0.f));
            mx.y = fmaxf(mx.y, fmaxf(h1, 0.f));
            mx.z = fmaxf(mx.z, fmaxf(h2, 0.f));
            mx.w = fmaxf(mx.w, fmaxf(h3, 0.f));
        }
    } else {
        // safety fallback: direct global reads, same math, halves split by eh
#pragma unroll 1
        for (int f = 0; f < 7; ++f) {
            int g = segStart[w][f], L = segLen[w][f];
            float a0 = 0.f, a1 = 0.f, a2 = 0.f, a3 = 0.f, svf = 0.f;
            for (int j = eh; j < L; j += 2) {
                int c = edge_col[g + j];
                float vp = edge_val[g + j] * scales[c];
                unsigned qv = *(const unsigned*)(supQ + (((unsigned)c) << 7) + f4x4);
                a0 = fmaf(vp, (float)( qv        & 0xffu), a0);
                a1 = fmaf(vp, (float)((qv >> 8)  & 0xffu), a1);
                a2 = fmaf(vp, (float)((qv >> 16) & 0xffu), a2);
                a3 = fmaf(vp, (float)( qv >> 24        ), a3);
                svf += vp;
            }
            a0 += __shfl_xor(a0, 32); a1 += __shfl_xor(a1, 32);
            a2 += __shfl_xor(a2, 32); a3 += __shfl_xor(a3, 32);
            svf += __shfl_xor(svf, 32);
            float h0 = fmaf(-128.f, svf, a0) + bb.x;
            float h1 = fmaf(-128.f, svf, a1) + bb.y;
            float h2 = fmaf(-128.f, svf, a2) + bb.z;
            float h3 = fmaf(-128.f, svf, a3) + bb.w;
            mx.x = fmaxf(mx.x, fmaxf(h0, 0.f));
            mx.y = fmaxf(mx.y, fmaxf(h1, 0.f));
            mx.z = fmaxf(mx.z, fmaxf(h2, 0.f));
            mx.w = fmaxf(mx.w, fmaxf(h3, 0.f));
        }
    }

    // --- cross-wave max exchange (halves are identical post-reduction) ---
    if (eh == 0) xch[w][f4] = mx;
    __syncthreads();
    float4 m0 = xch[0][f4], m1 = xch[1][f4];
    float o0 = fmaxf(m0.x, m1.x);
    float o1 = fmaxf(m0.y, m1.y);
    float o2 = fmaxf(m0.z, m1.z);
    float o3 = fmaxf(m0.w, m1.w);

    // --- log_softmax over 128 feats (reduce across the 32 f4 groups) ---
    float M = fmaxf(fmaxf(o0, o1), fmaxf(o2, o3));
#pragma unroll
    for (int o = 16; o >= 1; o >>= 1) M = fmaxf(M, __shfl_xor(M, o));
    float S = __expf(o0 - M) + __expf(o1 - M) + __expf(o2 - M) + __expf(o3 - M);
#pragma unroll
    for (int o = 16; o >= 1; o >>= 1) S += __shfl_xor(S, o);

    if (w == 0 && eh == 0) {
        float ls = __logf(S);
        *(float4*)&out[i * 128 + f4 * 4] =
            make_float4(o0 - M - ls, o1 - M - ls, o2 - M - ls, o3 - M - ls);
    }
}

// ---------------------------------------------------------------------------
extern "C" void kernel_launch(void* const* d_in, const int* in_sizes, int n_in,
                              void* d_out, int out_size, void* d_ws, size_t ws_size,
                              hipStream_t stream) {
    const float* x        = (const float*)d_in[0];
    const float* W        = (const float*)d_in[1];
    const float* b        = (const float*)d_in[2];
    const float* edge_val = (const float*)d_in[3];
    const int*   edge_row = (const int*)d_in[4];
    const int*   edge_col = (const int*)d_in[5];
    float* out = (float*)d_out;

    char* ws = (char*)d_ws;
    unsigned char*  supQ    = (unsigned char*)ws;                   // 17,920,000 B
    float*          scales  = (float*)(ws + 17920000);              //    560,000 B
    int*            row_ptr = (int*)(ws + 18480000);                //    560,004 B

    gemm_prep_kernel<<<GEMM_GRID + EDGE_BLOCKS, 256, 0, stream>>>(
        x, W, edge_row, row_ptr, supQ, scales);
    agg_kernel<<<NODES_PER_FRAME, 128, 0, stream>>>(
        supQ, scales, b, edge_val, edge_col, row_ptr, out);
}

// Round 2
// 246.737 us; speedup vs baseline: 1.0229x; 1.0229x over previous
//
#include <hip/hip_runtime.h>
#include <hip/hip_bf16.h>

#define N_NODES 140000
#define N_EDGES 2240000
#define NFEAT 128
#define NHID 128
#define N_FRAMES 14
#define NODES_PER_FRAME 10000
#define CAP 352            // int2 LDS slots per wave (7 frames padded to x8)

#define N_TILES 8750       // N_NODES / 16, exact
#define GEMM_GRID 1024     // 4 blocks/CU by LDS (34.8 KB) -> fully resident
#define WT_STRIDE 136

typedef __attribute__((ext_vector_type(8))) short frag_b16;
typedef __attribute__((ext_vector_type(4))) int frag_i4;
typedef __attribute__((ext_vector_type(4))) float f32x4;

__device__ __forceinline__ unsigned short f2bf(float f) {
    union { float f; unsigned int u; } v; v.f = f;
    unsigned int r = v.u + 0x7fffu + ((v.u >> 16) & 1u);   // RNE
    return (unsigned short)(r >> 16);
}
__device__ __forceinline__ int pk_bf16(float a, float b) {
    union { __hip_bfloat162 h; int i; } u;
    u.h = __float22bfloat162_rn(make_float2(a, b));        // v_cvt_pk_bf16_f32
    return u.i;
}

// ---------------------------------------------------------------------------
// Tiny prep: W (f32) -> WT (bf16, transposed) in global. 64 KB read, 32 KB
// written; ~3 us. Keeps per-GEMM-block staging conflict-free (uint4 path).
// ---------------------------------------------------------------------------
__global__ __launch_bounds__(256) void wt_kernel(
        const float* __restrict__ W, unsigned short* __restrict__ WT) {
    int e = blockIdx.x * 256 + threadIdx.x;            // 64 blocks -> 16384
    int k = e >> 7, n = e & 127;
    WT[n * 128 + k] = f2bf(W[e]);
}

// ---------------------------------------------------------------------------
// GEMM: support = x @ W via mfma_f32_16x16x32_bf16, int8 row-quant epilogue.
//  - WT (bf16) staged once per block via uint4 (conflict-free, round-0 path)
//  - grid-stride over 16-row tiles with register-double-buffered x prefetch
//  - NEW: 4x4 register transpose across q-groups so each lane stores one
//    uint4 of a single row -> supQ writes are full 64B lines (was 16x16B
//    partial-line scatter per store; WRITE_SIZE 114 MB -> ~19 MB)
//  - CSR row_ptr scan folded in as a grid-stride epilogue (no LDS-starved
//    tail blocks, no extra launch)
// ---------------------------------------------------------------------------
__global__ __launch_bounds__(256, 4) void gemm_kernel(
        const float* __restrict__ x, const unsigned short* __restrict__ WT,
        const int* __restrict__ edge_row, int* __restrict__ row_ptr,
        unsigned char* __restrict__ supQ, float* __restrict__ scales) {
    __shared__ unsigned short wt_lds[128 * WT_STRIDE];

    const int wave = threadIdx.x >> 6;
    const int lane = threadIdx.x & 63;
    const int m = lane & 15;
    const int q = lane >> 4;
    const bool qb0 = (q & 1);                          // q bit 0
    const bool qb1 = (q & 2);                          // q bit 1

    // --- issue first tile's x loads before WT staging (all in flight) ---
    int tile = blockIdx.x * 4 + wave;
    float4 pf[8];
    {
        const float* xr = x + (long)(tile * 16 + m) * 128 + q * 8;
#pragma unroll
        for (int ks = 0; ks < 4; ++ks) {
            pf[2 * ks]     = *(const float4*)(xr + ks * 32);
            pf[2 * ks + 1] = *(const float4*)(xr + ks * 32 + 4);
        }
    }

    // --- stage WT into LDS (uint4, conflict-free) ---
    const uint4* WTv = (const uint4*)WT;               // 2048 uint4
    for (int idx = threadIdx.x; idx < 2048; idx += 256) {
        uint4 d = WTv[idx];
        int elem = idx << 3;
        int n = elem >> 7, k = elem & 127;
        *(uint4*)&wt_lds[n * WT_STRIDE + k] = d;
    }
    __syncthreads();

    for (;;) {
        // convert current tile's x to bf16 fragments
        frag_b16 xa[4];
#pragma unroll
        for (int ks = 0; ks < 4; ++ks) {
            union { frag_b16 f; frag_i4 i; } u;
            u.i[0] = pk_bf16(pf[2 * ks].x, pf[2 * ks].y);
            u.i[1] = pk_bf16(pf[2 * ks].z, pf[2 * ks].w);
            u.i[2] = pk_bf16(pf[2 * ks + 1].x, pf[2 * ks + 1].y);
            u.i[3] = pk_bf16(pf[2 * ks + 1].z, pf[2 * ks + 1].w);
            xa[ks] = u.f;
        }

        // prefetch next tile's x (hides under MFMA + epilogue)
        const int next = tile + GEMM_GRID * 4;
        const bool more = next < N_TILES;
        if (more) {
            const float* xr = x + (long)(next * 16 + m) * 128 + q * 8;
#pragma unroll
            for (int ks = 0; ks < 4; ++ks) {
                pf[2 * ks]     = *(const float4*)(xr + ks * 32);
                pf[2 * ks + 1] = *(const float4*)(xr + ks * 32 + 4);
            }
        }

        f32x4 acc[8];
#pragma unroll
        for (int t = 0; t < 8; ++t) acc[t] = (f32x4){0.f, 0.f, 0.f, 0.f};

#pragma unroll
        for (int t = 0; t < 8; ++t) {
            const unsigned short* bp = &wt_lds[(t * 16 + m) * WT_STRIDE + q * 8];
#pragma unroll
            for (int ks = 0; ks < 4; ++ks) {
                frag_b16 wfrag = *(const frag_b16*)(bp + ks * 32);
                acc[t] = __builtin_amdgcn_mfma_f32_16x16x32_bf16(wfrag, xa[ks], acc[t], 0, 0, 0);
            }
        }

        // --- int8 row quantization epilogue ---
        float amax = 0.f;
#pragma unroll
        for (int t = 0; t < 8; ++t)
#pragma unroll
            for (int r = 0; r < 4; ++r) amax = fmaxf(amax, fabsf(acc[t][r]));
        amax = fmaxf(amax, __shfl_xor(amax, 16));
        amax = fmaxf(amax, __shfl_xor(amax, 32));
        float rinv = amax > 0.f ? 127.f / amax : 0.f;

        long node = (long)tile * 16 + m;
        if (q == 0) scales[node] = amax * (1.f / 127.f);

        // pack each acc quad into one dword (same bytes as before)
        unsigned dw[8];
#pragma unroll
        for (int t = 0; t < 8; ++t) {
            unsigned u0 = (unsigned)(rintf(acc[t][0] * rinv) + 128.f);
            unsigned u1 = (unsigned)(rintf(acc[t][1] * rinv) + 128.f);
            unsigned u2 = (unsigned)(rintf(acc[t][2] * rinv) + 128.f);
            unsigned u3 = (unsigned)(rintf(acc[t][3] * rinv) + 128.f);
            dw[t] = u0 | (u1 << 8) | (u2 << 16) | (u3 << 24);
        }

        // --- 4x4 transpose across q-groups (twice: t=0..3 and t=4..7) so
        //     lane (m,q) holds row m's dwords [4q .. 4q+3] -> coalesced store
        unsigned char* srow = supQ + node * 128;
#pragma unroll
        for (int h = 0; h < 2; ++h) {
            unsigned r0 = dw[4 * h + 0], r1 = dw[4 * h + 1];
            unsigned r2 = dw[4 * h + 2], r3 = dw[4 * h + 3];
            // stage 1: xor 16 (flip q bit0)
            unsigned g1 = __shfl_xor(qb0 ? r0 : r1, 16);
            unsigned g2 = __shfl_xor(qb0 ? r2 : r3, 16);
            unsigned c0 = qb0 ? g1 : r0;
            unsigned c1 = qb0 ? r1 : g1;
            unsigned c2 = qb0 ? g2 : r2;
            unsigned c3 = qb0 ? r3 : g2;
            // stage 2: xor 32 (flip q bit1)
            unsigned g3 = __shfl_xor(qb1 ? c0 : c2, 32);
            unsigned g4 = __shfl_xor(qb1 ? c1 : c3, 32);
            uint4 o;
            o.x = qb1 ? g3 : c0;
            o.y = qb1 ? g4 : c1;
            o.z = qb1 ? c2 : g3;
            o.w = qb1 ? c3 : g4;
            *(uint4*)(srow + h * 64 + q * 16) = o;     // full 64B lines/wave
        }

        if (!more) break;
        tile = next;
    }

    // --- CSR row_ptr from sorted COO rows: grid-stride epilogue ---
    for (int e = blockIdx.x * 256 + threadIdx.x; e < N_EDGES;
         e += GEMM_GRID * 256) {
        int r = edge_row[e];
        int prev = (e == 0) ? -1 : edge_row[e - 1];
        for (int qq = prev + 1; qq <= r; ++qq) row_ptr[qq] = e;
        if (e == N_EDGES - 1) {
            for (int qq = r + 1; qq <= N_NODES; ++qq) row_ptr[qq] = N_EDGES;
        }
    }
}

// ---------------------------------------------------------------------------
// Fused aggregation v3 (unchanged from verified 67 us version).
// Block = 128 thr = 2 waves = 1 output node. Wave w: frames [7w, 7w+6].
// ---------------------------------------------------------------------------
__global__ __launch_bounds__(128) void agg_kernel(
        const unsigned char* __restrict__ supQ, const float* __restrict__ scales,
        const float* __restrict__ b,
        const float* __restrict__ edge_val, const int* __restrict__ edge_col,
        const int* __restrict__ row_ptr, float* __restrict__ out) {
    __shared__ int    segStart[2][8];
    __shared__ int    segLen[2][8];
    __shared__ int    segOff[2][8];
    __shared__ int2   eBuf[2][CAP];
    __shared__ float4 xch[2][32];

    const int i = blockIdx.x;
    const int lane = threadIdx.x & 63;
    const int w = threadIdx.x >> 6;
    const int eh = lane >> 5;                          // which edge of a pair
    const int f4 = lane & 31;                          // feature quad
    const unsigned f4x4 = (unsigned)f4 * 4u;

    // --- CSR ranges in lanes 0..6; padded-to-8 exclusive scan ---
    int a = 0, len = 0;
    if (lane < 7) {
        int n = (w * 7 + lane) * NODES_PER_FRAME + i;
        a = row_ptr[n];
        len = row_ptr[n + 1] - a;
    }
    int len8 = (len + 7) & ~7;
    int off = 0;
#pragma unroll
    for (int f2 = 0; f2 < 7; ++f2) {
        int L2 = __shfl(len8, f2);
        if (f2 < lane) off += L2;
    }
    if (lane < 7) { segStart[w][lane] = a; segLen[w][lane] = len; segOff[w][lane] = off; }
    if (lane == 6) segOff[w][7] = off + len8;
    __syncthreads();

    const bool fit = segOff[w][7] <= CAP;              // wave-uniform

    // --- stage (col, val'=val*scale[col]) into LDS, zero-padded per frame ---
    if (fit) {
#pragma unroll 1
        for (int f = 0; f < 7; ++f) {
            int g = segStart[w][f], s = segOff[w][f], L = segLen[w][f];
            int L8 = (L + 7) & ~7;
            for (int j = lane; j < L8; j += 64) {
                int2 v = make_int2(0, 0);
                if (j < L) {
                    int c = edge_col[g + j];
                    v.x = c;
                    v.y = __float_as_int(edge_val[g + j] * scales[c]);
                }
                eBuf[w][s + j] = v;
            }
        }
    }
    __syncthreads();

    const float4 bb = *(const float4*)&b[f4 * 4];
    float4 mx = make_float4(0.f, 0.f, 0.f, 0.f);       // relu => max >= 0

    if (fit) {
#pragma unroll 1
        for (int f = 0; f < 7; ++f) {
            int s = segOff[w][f];
            int e8 = s + ((segLen[w][f] + 7) & ~7);
            float a0 = 0.f, a1 = 0.f, a2 = 0.f, a3 = 0.f, svf = 0.f;
            for (int j = s; j < e8; j += 8) {
                int2 ed[4];
#pragma unroll
                for (int p = 0; p < 4; ++p) ed[p] = eBuf[w][j + 2 * p + eh];
                unsigned q4[4];
#pragma unroll
                for (int p = 0; p < 4; ++p)
                    q4[p] = *(const unsigned*)(supQ + (((unsigned)ed[p].x) << 7) + f4x4);
#pragma unroll
                for (int p = 0; p < 4; ++p) {
                    float vp = __int_as_float(ed[p].y);
                    a0 = fmaf(vp, (float)( q4[p]        & 0xffu), a0);
                    a1 = fmaf(vp, (float)((q4[p] >> 8)  & 0xffu), a1);
                    a2 = fmaf(vp, (float)((q4[p] >> 16) & 0xffu), a2);
                    a3 = fmaf(vp, (float)( q4[p] >> 24        ), a3);
                    svf += vp;
                }
            }
            a0 += __shfl_xor(a0, 32); a1 += __shfl_xor(a1, 32);
            a2 += __shfl_xor(a2, 32); a3 += __shfl_xor(a3, 32);
            svf += __shfl_xor(svf, 32);
            float h0 = fmaf(-128.f, svf, a0) + bb.x;
            float h1 = fmaf(-128.f, svf, a1) + bb.y;
            float h2 = fmaf(-128.f, svf, a2) + bb.z;
            float h3 = fmaf(-128.f, svf, a3) + bb.w;
            mx.x = fmaxf(mx.x, fmaxf(h0, 0.f));
            mx.y = fmaxf(mx.y, fmaxf(h1, 0.f));
            mx.z = fmaxf(mx.z, fmaxf(h2, 0.f));
            mx.w = fmaxf(mx.w, fmaxf(h3, 0.f));
        }
    } else {
        // safety fallback: direct global reads, same math, halves split by eh
#pragma unroll 1
        for (int f = 0; f < 7; ++f) {
            int g = segStart[w][f], L = segLen[w][f];
            float a0 = 0.f, a1 = 0.f, a2 = 0.f, a3 = 0.f, svf = 0.f;
            for (int j = eh; j < L; j += 2) {
                int c = edge_col[g + j];
                float vp = edge_val[g + j] * scales[c];
                unsigned qv = *(const unsigned*)(supQ + (((unsigned)c) << 7) + f4x4);
                a0 = fmaf(vp, (float)( qv        & 0xffu), a0);
                a1 = fmaf(vp, (float)((qv >> 8)  & 0xffu), a1);
                a2 = fmaf(vp, (float)((qv >> 16) & 0xffu), a2);
                a3 = fmaf(vp, (float)( qv >> 24        ), a3);
                svf += vp;
            }
            a0 += __shfl_xor(a0, 32); a1 += __shfl_xor(a1, 32);
            a2 += __shfl_xor(a2, 32); a3 += __shfl_xor(a3, 32);
            svf += __shfl_xor(svf, 32);
            float h0 = fmaf(-128.f, svf, a0) + bb.x;
            float h1 = fmaf(-128.f, svf, a1) + bb.y;
            float h2 = fmaf(-128.f, svf, a2) + bb.z;
            float h3 = fmaf(-128.f, svf, a3) + bb.w;
            mx.x = fmaxf(mx.x, fmaxf(h0, 0.f));
            mx.y = fmaxf(mx.y, fmaxf(h1, 0.f));
            mx.z = fmaxf(mx.z, fmaxf(h2, 0.f));
            mx.w = fmaxf(mx.w, fmaxf(h3, 0.f));
        }
    }

    // --- cross-wave max exchange (halves are identical post-reduction) ---
    if (eh == 0) xch[w][f4] = mx;
    __syncthreads();
    float4 m0 = xch[0][f4], m1 = xch[1][f4];
    float o0 = fmaxf(m0.x, m1.x);
    float o1 = fmaxf(m0.y, m1.y);
    float o2 = fmaxf(m0.z, m1.z);
    float o3 = fmaxf(m0.w, m1.w);

    // --- log_softmax over 128 feats (reduce across the 32 f4 groups) ---
    float M = fmaxf(fmaxf(o0, o1), fmaxf(o2, o3));
#pragma unroll
    for (int o = 16; o >= 1; o >>= 1) M = fmaxf(M, __shfl_xor(M, o));
    float S = __expf(o0 - M) + __expf(o1 - M) + __expf(o2 - M) + __expf(o3 - M);
#pragma unroll
    for (int o = 16; o >= 1; o >>= 1) S += __shfl_xor(S, o);

    if (w == 0 && eh == 0) {
        float ls = __logf(S);
        *(float4*)&out[i * 128 + f4 * 4] =
            make_float4(o0 - M - ls, o1 - M - ls, o2 - M - ls, o3 - M - ls);
    }
}

// ---------------------------------------------------------------------------
extern "C" void kernel_launch(void* const* d_in, const int* in_sizes, int n_in,
                              void* d_out, int out_size, void* d_ws, size_t ws_size,
                              hipStream_t stream) {
    const float* x        = (const float*)d_in[0];
    const float* W        = (const float*)d_in[1];
    const float* b        = (const float*)d_in[2];
    const float* edge_val = (const float*)d_in[3];
    const int*   edge_row = (const int*)d_in[4];
    const int*   edge_col = (const int*)d_in[5];
    float* out = (float*)d_out;

    char* ws = (char*)d_ws;
    unsigned char*  supQ    = (unsigned char*)ws;                   // 17,920,000 B
    float*          scales  = (float*)(ws + 17920000);              //    560,000 B
    unsigned short* WT      = (unsigned short*)(ws + 18480000);     //     32,768 B
    int*            row_ptr = (int*)(ws + 18512768);                //    560,004 B

    wt_kernel<<<64, 256, 0, stream>>>(W, WT);
    gemm_kernel<<<GEMM_GRID, 256, 0, stream>>>(x, WT, edge_row, row_ptr, supQ, scales);
    agg_kernel<<<NODES_PER_FRAME, 128, 0, stream>>>(supQ, scales, b, edge_val, edge_col, row_ptr, out);
}

// Round 3
// 203.339 us; speedup vs baseline: 1.2412x; 1.2134x over previous
//
#include <hip/hip_runtime.h>
#include <hip/hip_bf16.h>

#define N_NODES 140000
#define N_EDGES 2240000
#define NFEAT 128
#define NHID 128
#define N_FRAMES 14
#define NODES_PER_FRAME 10000
#define CAP 352            // int2 LDS slots per wave (7 frames padded to x8)

#define N_TILES 8750       // N_NODES / 16, exact
#define GEMM_GRID 1024     // 4 blocks/CU by LDS (34.8 KB) -> fully resident
#define WT_STRIDE 136

typedef __attribute__((ext_vector_type(8))) short frag_b16;
typedef __attribute__((ext_vector_type(4))) int frag_i4;
typedef __attribute__((ext_vector_type(4))) float f32x4;

__device__ __forceinline__ unsigned short f2bf(float f) {
    union { float f; unsigned int u; } v; v.f = f;
    unsigned int r = v.u + 0x7fffu + ((v.u >> 16) & 1u);   // RNE
    return (unsigned short)(r >> 16);
}
__device__ __forceinline__ int pk_bf16(float a, float b) {
    union { __hip_bfloat162 h; int i; } u;
    u.h = __float22bfloat162_rn(make_float2(a, b));        // v_cvt_pk_bf16_f32
    return u.i;
}

// ---------------------------------------------------------------------------
// Tiny prep: W (f32) -> WT (bf16, transposed) in global. 64 KB read, 32 KB
// written; ~3 us. Keeps per-GEMM-block staging conflict-free (uint4 path).
// ---------------------------------------------------------------------------
__global__ __launch_bounds__(256) void wt_kernel(
        const float* __restrict__ W, unsigned short* __restrict__ WT) {
    int e = blockIdx.x * 256 + threadIdx.x;            // 64 blocks -> 16384
    int k = e >> 7, n = e & 127;
    WT[n * 128 + k] = f2bf(W[e]);
}

// ---------------------------------------------------------------------------
// GEMM: support = x @ W via mfma_f32_16x16x32_bf16, int8 row-quant epilogue.
//  - WT (bf16) staged once per block via uint4 (conflict-free)
//  - grid-stride over 16-row tiles with register-double-buffered x prefetch
//  - 4x4 register transpose across q-groups -> coalesced full-line supQ stores
//  - CSR row_ptr scan folded in as a grid-stride epilogue
//  - NO min-occupancy clause: round-1/2's __launch_bounds__(256,4) capped the
//    allocator below the ~110 live VGPRs (reported 64) -> per-iteration
//    scratch spills = ~150 MB phantom HBM traffic (FETCH 137/WRITE 111 MB)
//    and MfmaUtil 1.9%. LDS (34.8 KB) already pins occupancy at 4 blocks/CU.
// ---------------------------------------------------------------------------
__global__ __launch_bounds__(256) void gemm_kernel(
        const float* __restrict__ x, const unsigned short* __restrict__ WT,
        const int* __restrict__ edge_row, int* __restrict__ row_ptr,
        unsigned char* __restrict__ supQ, float* __restrict__ scales) {
    __shared__ unsigned short wt_lds[128 * WT_STRIDE];

    const int wave = threadIdx.x >> 6;
    const int lane = threadIdx.x & 63;
    const int m = lane & 15;
    const int q = lane >> 4;
    const bool qb0 = (q & 1);                          // q bit 0
    const bool qb1 = (q & 2);                          // q bit 1

    // --- issue first tile's x loads before WT staging (all in flight) ---
    int tile = blockIdx.x * 4 + wave;
    float4 pf[8];
    {
        const float* xr = x + (long)(tile * 16 + m) * 128 + q * 8;
#pragma unroll
        for (int ks = 0; ks < 4; ++ks) {
            pf[2 * ks]     = *(const float4*)(xr + ks * 32);
            pf[2 * ks + 1] = *(const float4*)(xr + ks * 32 + 4);
        }
    }

    // --- stage WT into LDS (uint4, conflict-free) ---
    const uint4* WTv = (const uint4*)WT;               // 2048 uint4
    for (int idx = threadIdx.x; idx < 2048; idx += 256) {
        uint4 d = WTv[idx];
        int elem = idx << 3;
        int n = elem >> 7, k = elem & 127;
        *(uint4*)&wt_lds[n * WT_STRIDE + k] = d;
    }
    __syncthreads();

    for (;;) {
        // convert current tile's x to bf16 fragments (pf dies here)
        frag_b16 xa[4];
#pragma unroll
        for (int ks = 0; ks < 4; ++ks) {
            union { frag_b16 f; frag_i4 i; } u;
            u.i[0] = pk_bf16(pf[2 * ks].x, pf[2 * ks].y);
            u.i[1] = pk_bf16(pf[2 * ks].z, pf[2 * ks].w);
            u.i[2] = pk_bf16(pf[2 * ks + 1].x, pf[2 * ks + 1].y);
            u.i[3] = pk_bf16(pf[2 * ks + 1].z, pf[2 * ks + 1].w);
            xa[ks] = u.f;
        }

        // prefetch next tile's x (hides under MFMA + epilogue)
        const int next = tile + GEMM_GRID * 4;
        const bool more = next < N_TILES;
        if (more) {
            const float* xr = x + (long)(next * 16 + m) * 128 + q * 8;
#pragma unroll
            for (int ks = 0; ks < 4; ++ks) {
                pf[2 * ks]     = *(const float4*)(xr + ks * 32);
                pf[2 * ks + 1] = *(const float4*)(xr + ks * 32 + 4);
            }
        }

        f32x4 acc[8];
#pragma unroll
        for (int t = 0; t < 8; ++t) acc[t] = (f32x4){0.f, 0.f, 0.f, 0.f};

#pragma unroll
        for (int t = 0; t < 8; ++t) {
            const unsigned short* bp = &wt_lds[(t * 16 + m) * WT_STRIDE + q * 8];
#pragma unroll
            for (int ks = 0; ks < 4; ++ks) {
                frag_b16 wfrag = *(const frag_b16*)(bp + ks * 32);
                acc[t] = __builtin_amdgcn_mfma_f32_16x16x32_bf16(wfrag, xa[ks], acc[t], 0, 0, 0);
            }
        }

        // --- int8 row quantization epilogue ---
        float amax = 0.f;
#pragma unroll
        for (int t = 0; t < 8; ++t)
#pragma unroll
            for (int r = 0; r < 4; ++r) amax = fmaxf(amax, fabsf(acc[t][r]));
        amax = fmaxf(amax, __shfl_xor(amax, 16));
        amax = fmaxf(amax, __shfl_xor(amax, 32));
        float rinv = amax > 0.f ? 127.f / amax : 0.f;

        long node = (long)tile * 16 + m;
        if (q == 0) scales[node] = amax * (1.f / 127.f);

        // quantize+pack per half, 4x4 transpose across q-groups, store one
        // uint4 of a single row per lane -> full 64B lines per wave-store
        unsigned char* srow = supQ + node * 128;
#pragma unroll
        for (int h = 0; h < 2; ++h) {
            unsigned t4[4];
#pragma unroll
            for (int t = 0; t < 4; ++t) {
                const f32x4 av = acc[4 * h + t];
                unsigned u0 = (unsigned)(rintf(av[0] * rinv) + 128.f);
                unsigned u1 = (unsigned)(rintf(av[1] * rinv) + 128.f);
                unsigned u2 = (unsigned)(rintf(av[2] * rinv) + 128.f);
                unsigned u3 = (unsigned)(rintf(av[3] * rinv) + 128.f);
                t4[t] = u0 | (u1 << 8) | (u2 << 16) | (u3 << 24);
            }
            // stage 1: xor 16 (flip q bit0)
            unsigned g1 = __shfl_xor(qb0 ? t4[0] : t4[1], 16);
            unsigned g2 = __shfl_xor(qb0 ? t4[2] : t4[3], 16);
            unsigned c0 = qb0 ? g1 : t4[0];
            unsigned c1 = qb0 ? t4[1] : g1;
            unsigned c2 = qb0 ? g2 : t4[2];
            unsigned c3 = qb0 ? t4[3] : g2;
            // stage 2: xor 32 (flip q bit1)
            unsigned g3 = __shfl_xor(qb1 ? c0 : c2, 32);
            unsigned g4 = __shfl_xor(qb1 ? c1 : c3, 32);
            uint4 o;
            o.x = qb1 ? g3 : c0;
            o.y = qb1 ? g4 : c1;
            o.z = qb1 ? c2 : g3;
            o.w = qb1 ? c3 : g4;
            *(uint4*)(srow + h * 64 + q * 16) = o;
        }

        if (!more) break;
        tile = next;
    }

    // --- CSR row_ptr from sorted COO rows: grid-stride epilogue ---
    for (int e = blockIdx.x * 256 + threadIdx.x; e < N_EDGES;
         e += GEMM_GRID * 256) {
        int r = edge_row[e];
        int prev = (e == 0) ? -1 : edge_row[e - 1];
        for (int qq = prev + 1; qq <= r; ++qq) row_ptr[qq] = e;
        if (e == N_EDGES - 1) {
            for (int qq = r + 1; qq <= N_NODES; ++qq) row_ptr[qq] = N_EDGES;
        }
    }
}

// ---------------------------------------------------------------------------
// Fused aggregation v3 (unchanged from verified 67 us version).
// Block = 128 thr = 2 waves = 1 output node. Wave w: frames [7w, 7w+6].
// ---------------------------------------------------------------------------
__global__ __launch_bounds__(128) void agg_kernel(
        const unsigned char* __restrict__ supQ, const float* __restrict__ scales,
        const float* __restrict__ b,
        const float* __restrict__ edge_val, const int* __restrict__ edge_col,
        const int* __restrict__ row_ptr, float* __restrict__ out) {
    __shared__ int    segStart[2][8];
    __shared__ int    segLen[2][8];
    __shared__ int    segOff[2][8];
    __shared__ int2   eBuf[2][CAP];
    __shared__ float4 xch[2][32];

    const int i = blockIdx.x;
    const int lane = threadIdx.x & 63;
    const int w = threadIdx.x >> 6;
    const int eh = lane >> 5;                          // which edge of a pair
    const int f4 = lane & 31;                          // feature quad
    const unsigned f4x4 = (unsigned)f4 * 4u;

    // --- CSR ranges in lanes 0..6; padded-to-8 exclusive scan ---
    int a = 0, len = 0;
    if (lane < 7) {
        int n = (w * 7 + lane) * NODES_PER_FRAME + i;
        a = row_ptr[n];
        len = row_ptr[n + 1] - a;
    }
    int len8 = (len + 7) & ~7;
    int off = 0;
#pragma unroll
    for (int f2 = 0; f2 < 7; ++f2) {
        int L2 = __shfl(len8, f2);
        if (f2 < lane) off += L2;
    }
    if (lane < 7) { segStart[w][lane] = a; segLen[w][lane] = len; segOff[w][lane] = off; }
    if (lane == 6) segOff[w][7] = off + len8;
    __syncthreads();

    const bool fit = segOff[w][7] <= CAP;              // wave-uniform

    // --- stage (col, val'=val*scale[col]) into LDS, zero-padded per frame ---
    if (fit) {
#pragma unroll 1
        for (int f = 0; f < 7; ++f) {
            int g = segStart[w][f], s = segOff[w][f], L = segLen[w][f];
            int L8 = (L + 7) & ~7;
            for (int j = lane; j < L8; j += 64) {
                int2 v = make_int2(0, 0);
                if (j < L) {
                    int c = edge_col[g + j];
                    v.x = c;
                    v.y = __float_as_int(edge_val[g + j] * scales[c]);
                }
                eBuf[w][s + j] = v;
            }
        }
    }
    __syncthreads();

    const float4 bb = *(const float4*)&b[f4 * 4];
    float4 mx = make_float4(0.f, 0.f, 0.f, 0.f);       // relu => max >= 0

    if (fit) {
#pragma unroll 1
        for (int f = 0; f < 7; ++f) {
            int s = segOff[w][f];
            int e8 = s + ((segLen[w][f] + 7) & ~7);
            float a0 = 0.f, a1 = 0.f, a2 = 0.f, a3 = 0.f, svf = 0.f;
            for (int j = s; j < e8; j += 8) {
                int2 ed[4];
#pragma unroll
                for (int p = 0; p < 4; ++p) ed[p] = eBuf[w][j + 2 * p + eh];
                unsigned q4[4];
#pragma unroll
                for (int p = 0; p < 4; ++p)
                    q4[p] = *(const unsigned*)(supQ + (((unsigned)ed[p].x) << 7) + f4x4);
#pragma unroll
                for (int p = 0; p < 4; ++p) {
                    float vp = __int_as_float(ed[p].y);
                    a0 = fmaf(vp, (float)( q4[p]        & 0xffu), a0);
                    a1 = fmaf(vp, (float)((q4[p] >> 8)  & 0xffu), a1);
                    a2 = fmaf(vp, (float)((q4[p] >> 16) & 0xffu), a2);
                    a3 = fmaf(vp, (float)( q4[p] >> 24        ), a3);
                    svf += vp;
                }
            }
            a0 += __shfl_xor(a0, 32); a1 += __shfl_xor(a1, 32);
            a2 += __shfl_xor(a2, 32); a3 += __shfl_xor(a3, 32);
            svf += __shfl_xor(svf, 32);
            float h0 = fmaf(-128.f, svf, a0) + bb.x;
            float h1 = fmaf(-128.f, svf, a1) + bb.y;
            float h2 = fmaf(-128.f, svf, a2) + bb.z;
            float h3 = fmaf(-128.f, svf, a3) + bb.w;
            mx.x = fmaxf(mx.x, fmaxf(h0, 0.f));
            mx.y = fmaxf(mx.y, fmaxf(h1, 0.f));
            mx.z = fmaxf(mx.z, fmaxf(h2, 0.f));
            mx.w = fmaxf(mx.w, fmaxf(h3, 0.f));
        }
    } else {
        // safety fallback: direct global reads, same math, halves split by eh
#pragma unroll 1
        for (int f = 0; f < 7; ++f) {
            int g = segStart[w][f], L = segLen[w][f];
            float a0 = 0.f, a1 = 0.f, a2 = 0.f, a3 = 0.f, svf = 0.f;
            for (int j = eh; j < L; j += 2) {
                int c = edge_col[g + j];
                float vp = edge_val[g + j] * scales[c];
                unsigned qv = *(const unsigned*)(supQ + (((unsigned)c) << 7) + f4x4);
                a0 = fmaf(vp, (float)( qv        & 0xffu), a0);
                a1 = fmaf(vp, (float)((qv >> 8)  & 0xffu), a1);
                a2 = fmaf(vp, (float)((qv >> 16) & 0xffu), a2);
                a3 = fmaf(vp, (float)( qv >> 24        ), a3);
                svf += vp;
            }
            a0 += __shfl_xor(a0, 32); a1 += __shfl_xor(a1, 32);
            a2 += __shfl_xor(a2, 32); a3 += __shfl_xor(a3, 32);
            svf += __shfl_xor(svf, 32);
            float h0 = fmaf(-128.f, svf, a0) + bb.x;
            float h1 = fmaf(-128.f, svf, a1) + bb.y;
            float h2 = fmaf(-128.f, svf, a2) + bb.z;
            float h3 = fmaf(-128.f, svf, a3) + bb.w;
            mx.x = fmaxf(mx.x, fmaxf(h0, 0.f));
            mx.y = fmaxf(mx.y, fmaxf(h1, 0.f));
            mx.z = fmaxf(mx.z, fmaxf(h2, 0.f));
            mx.w = fmaxf(mx.w, fmaxf(h3, 0.f));
        }
    }

    // --- cross-wave max exchange (halves are identical post-reduction) ---
    if (eh == 0) xch[w][f4] = mx;
    __syncthreads();
    float4 m0 = xch[0][f4], m1 = xch[1][f4];
    float o0 = fmaxf(m0.x, m1.x);
    float o1 = fmaxf(m0.y, m1.y);
    float o2 = fmaxf(m0.z, m1.z);
    float o3 = fmaxf(m0.w, m1.w);

    // --- log_softmax over 128 feats (reduce across the 32 f4 groups) ---
    float M = fmaxf(fmaxf(o0, o1), fmaxf(o2, o3));
#pragma unroll
    for (int o = 16; o >= 1; o >>= 1) M = fmaxf(M, __shfl_xor(M, o));
    float S = __expf(o0 - M) + __expf(o1 - M) + __expf(o2 - M) + __expf(o3 - M);
#pragma unroll
    for (int o = 16; o >= 1; o >>= 1) S += __shfl_xor(S, o);

    if (w == 0 && eh == 0) {
        float ls = __logf(S);
        *(float4*)&out[i * 128 + f4 * 4] =
            make_float4(o0 - M - ls, o1 - M - ls, o2 - M - ls, o3 - M - ls);
    }
}

// ---------------------------------------------------------------------------
extern "C" void kernel_launch(void* const* d_in, const int* in_sizes, int n_in,
                              void* d_out, int out_size, void* d_ws, size_t ws_size,
                              hipStream_t stream) {
    const float* x        = (const float*)d_in[0];
    const float* W        = (const float*)d_in[1];
    const float* b        = (const float*)d_in[2];
    const float* edge_val = (const float*)d_in[3];
    const int*   edge_row = (const int*)d_in[4];
    const int*   edge_col = (const int*)d_in[5];
    float* out = (float*)d_out;

    char* ws = (char*)d_ws;
    unsigned char*  supQ    = (unsigned char*)ws;                   // 17,920,000 B
    float*          scales  = (float*)(ws + 17920000);              //    560,000 B
    unsigned short* WT      = (unsigned short*)(ws + 18480000);     //     32,768 B
    int*            row_ptr = (int*)(ws + 18512768);                //    560,004 B

    wt_kernel<<<64, 256, 0, stream>>>(W, WT);
    gemm_kernel<<<GEMM_GRID, 256, 0, stream>>>(x, WT, edge_row, row_ptr, supQ, scales);
    agg_kernel<<<NODES_PER_FRAME, 128, 0, stream>>>(supQ, scales, b, edge_val, edge_col, row_ptr, out);
}

// Round 4
// 196.974 us; speedup vs baseline: 1.2813x; 1.0323x over previous
//
#include <hip/hip_runtime.h>
#include <hip/hip_bf16.h>

#define N_NODES 140000
#define N_EDGES 2240000
#define NFEAT 128
#define NHID 128
#define N_FRAMES 14
#define NODES_PER_FRAME 10000
#define CAP 352            // int2 LDS slots per wave (7 frames padded to x8)

#define N_TILES 8750       // N_NODES / 16, exact
#define GEMM_GRID 512      // 512-thr blocks: 2 blocks/CU (LDS+VGPR), 16 waves/CU
#define WAVES_PER_BLOCK 8
#define WT_STRIDE 136
#define EDGE_BLOCKS ((N_EDGES + 255) / 256)

typedef __attribute__((ext_vector_type(8))) short frag_b16;
typedef __attribute__((ext_vector_type(4))) int frag_i4;
typedef __attribute__((ext_vector_type(4))) float f32x4;

__device__ __forceinline__ unsigned short f2bf(float f) {
    union { float f; unsigned int u; } v; v.f = f;
    unsigned int r = v.u + 0x7fffu + ((v.u >> 16) & 1u);   // RNE
    return (unsigned short)(r >> 16);
}
__device__ __forceinline__ int pk_bf16(float a, float b) {
    union { __hip_bfloat162 h; int i; } u;
    u.h = __float22bfloat162_rn(make_float2(a, b));        // v_cvt_pk_bf16_f32
    return u.i;
}

// ---------------------------------------------------------------------------
// Prep: blocks [0,64): W (f32) -> WT (bf16, transposed) in global.
//       blocks [64, ...): CSR row_ptr from sorted COO rows.
// No LDS, tiny VGPR -> full occupancy; runs in ~3-4 us. Moving the row_ptr
// scan here takes it off gemm's serial tail.
// ---------------------------------------------------------------------------
__global__ __launch_bounds__(256) void prep_kernel(
        const float* __restrict__ W, unsigned short* __restrict__ WT,
        const int* __restrict__ edge_row, int* __restrict__ row_ptr) {
    if (blockIdx.x < 64) {
        int e = blockIdx.x * 256 + threadIdx.x;        // 16384 = NFEAT*NHID
        int k = e >> 7, n = e & 127;
        WT[n * 128 + k] = f2bf(W[e]);
        return;
    }
    int e = (blockIdx.x - 64) * 256 + threadIdx.x;
    if (e < N_EDGES) {
        int r = edge_row[e];
        int prev = (e == 0) ? -1 : edge_row[e - 1];
        for (int q = prev + 1; q <= r; ++q) row_ptr[q] = e;
        if (e == N_EDGES - 1) {
            for (int q = r + 1; q <= N_NODES; ++q) row_ptr[q] = N_EDGES;
        }
    }
}

// ---------------------------------------------------------------------------
// GEMM: support = x @ W via mfma_f32_16x16x32_bf16, int8 row-quant epilogue.
//  - 512-thread blocks: 8 waves share ONE WT staging (was 4) -> staging
//    traffic and prologue latency per CU halved; occupancy unchanged
//    (VGPR ~110 caps 4 waves/SIMD regardless of block size).
//  - grid-stride over 16-row tiles with register-double-buffered x prefetch
//  - 4x4 register transpose across q-groups -> coalesced full-line supQ stores
//  - NO min-occupancy clause (round-2 lesson: (256,4) forced VGPR=64 ->
//    ~150 MB of scratch-spill HBM traffic).
// ---------------------------------------------------------------------------
__global__ __launch_bounds__(512) void gemm_kernel(
        const float* __restrict__ x, const unsigned short* __restrict__ WT,
        unsigned char* __restrict__ supQ, float* __restrict__ scales) {
    __shared__ unsigned short wt_lds[128 * WT_STRIDE];

    const int wave = threadIdx.x >> 6;
    const int lane = threadIdx.x & 63;
    const int m = lane & 15;
    const int q = lane >> 4;
    const bool qb0 = (q & 1);                          // q bit 0
    const bool qb1 = (q & 2);                          // q bit 1

    // --- issue first tile's x loads before WT staging (all in flight) ---
    int tile = blockIdx.x * WAVES_PER_BLOCK + wave;
    float4 pf[8];
    {
        const float* xr = x + (long)(tile * 16 + m) * 128 + q * 8;
#pragma unroll
        for (int ks = 0; ks < 4; ++ks) {
            pf[2 * ks]     = *(const float4*)(xr + ks * 32);
            pf[2 * ks + 1] = *(const float4*)(xr + ks * 32 + 4);
        }
    }

    // --- stage WT into LDS (uint4, conflict-free) ---
    const uint4* WTv = (const uint4*)WT;               // 2048 uint4
    for (int idx = threadIdx.x; idx < 2048; idx += 512) {
        uint4 d = WTv[idx];
        int elem = idx << 3;
        int n = elem >> 7, k = elem & 127;
        *(uint4*)&wt_lds[n * WT_STRIDE + k] = d;
    }
    __syncthreads();

    for (;;) {
        // convert current tile's x to bf16 fragments (pf dies here)
        frag_b16 xa[4];
#pragma unroll
        for (int ks = 0; ks < 4; ++ks) {
            union { frag_b16 f; frag_i4 i; } u;
            u.i[0] = pk_bf16(pf[2 * ks].x, pf[2 * ks].y);
            u.i[1] = pk_bf16(pf[2 * ks].z, pf[2 * ks].w);
            u.i[2] = pk_bf16(pf[2 * ks + 1].x, pf[2 * ks + 1].y);
            u.i[3] = pk_bf16(pf[2 * ks + 1].z, pf[2 * ks + 1].w);
            xa[ks] = u.f;
        }

        // prefetch next tile's x (hides under MFMA + epilogue)
        const int next = tile + GEMM_GRID * WAVES_PER_BLOCK;
        const bool more = next < N_TILES;
        if (more) {
            const float* xr = x + (long)(next * 16 + m) * 128 + q * 8;
#pragma unroll
            for (int ks = 0; ks < 4; ++ks) {
                pf[2 * ks]     = *(const float4*)(xr + ks * 32);
                pf[2 * ks + 1] = *(const float4*)(xr + ks * 32 + 4);
            }
        }

        f32x4 acc[8];
#pragma unroll
        for (int t = 0; t < 8; ++t) acc[t] = (f32x4){0.f, 0.f, 0.f, 0.f};

#pragma unroll
        for (int t = 0; t < 8; ++t) {
            const unsigned short* bp = &wt_lds[(t * 16 + m) * WT_STRIDE + q * 8];
#pragma unroll
            for (int ks = 0; ks < 4; ++ks) {
                frag_b16 wfrag = *(const frag_b16*)(bp + ks * 32);
                acc[t] = __builtin_amdgcn_mfma_f32_16x16x32_bf16(wfrag, xa[ks], acc[t], 0, 0, 0);
            }
        }

        // --- int8 row quantization epilogue ---
        float amax = 0.f;
#pragma unroll
        for (int t = 0; t < 8; ++t)
#pragma unroll
            for (int r = 0; r < 4; ++r) amax = fmaxf(amax, fabsf(acc[t][r]));
        amax = fmaxf(amax, __shfl_xor(amax, 16));
        amax = fmaxf(amax, __shfl_xor(amax, 32));
        float rinv = amax > 0.f ? 127.f / amax : 0.f;

        long node = (long)tile * 16 + m;
        if (q == 0) scales[node] = amax * (1.f / 127.f);

        // quantize+pack per half, 4x4 transpose across q-groups, store one
        // uint4 of a single row per lane -> full 64B lines per wave-store
        unsigned char* srow = supQ + node * 128;
#pragma unroll
        for (int h = 0; h < 2; ++h) {
            unsigned t4[4];
#pragma unroll
            for (int t = 0; t < 4; ++t) {
                const f32x4 av = acc[4 * h + t];
                unsigned u0 = (unsigned)(rintf(av[0] * rinv) + 128.f);
                unsigned u1 = (unsigned)(rintf(av[1] * rinv) + 128.f);
                unsigned u2 = (unsigned)(rintf(av[2] * rinv) + 128.f);
                unsigned u3 = (unsigned)(rintf(av[3] * rinv) + 128.f);
                t4[t] = u0 | (u1 << 8) | (u2 << 16) | (u3 << 24);
            }
            // stage 1: xor 16 (flip q bit0)
            unsigned g1 = __shfl_xor(qb0 ? t4[0] : t4[1], 16);
            unsigned g2 = __shfl_xor(qb0 ? t4[2] : t4[3], 16);
            unsigned c0 = qb0 ? g1 : t4[0];
            unsigned c1 = qb0 ? t4[1] : g1;
            unsigned c2 = qb0 ? g2 : t4[2];
            unsigned c3 = qb0 ? t4[3] : g2;
            // stage 2: xor 32 (flip q bit1)
            unsigned g3 = __shfl_xor(qb1 ? c0 : c2, 32);
            unsigned g4 = __shfl_xor(qb1 ? c1 : c3, 32);
            uint4 o;
            o.x = qb1 ? g3 : c0;
            o.y = qb1 ? g4 : c1;
            o.z = qb1 ? c2 : g3;
            o.w = qb1 ? c3 : g4;
            *(uint4*)(srow + h * 64 + q * 16) = o;
        }

        if (!more) break;
        tile = next;
    }
}

// ---------------------------------------------------------------------------
// Fused aggregation v3 (unchanged from verified 66 us version).
// Block = 128 thr = 2 waves = 1 output node. Wave w: frames [7w, 7w+6].
// At its gather roofline: 149 MB L2-miss @ ~2.35 TB/s random-fill ceiling.
// ---------------------------------------------------------------------------
__global__ __launch_bounds__(128) void agg_kernel(
        const unsigned char* __restrict__ supQ, const float* __restrict__ scales,
        const float* __restrict__ b,
        const float* __restrict__ edge_val, const int* __restrict__ edge_col,
        const int* __restrict__ row_ptr, float* __restrict__ out) {
    __shared__ int    segStart[2][8];
    __shared__ int    segLen[2][8];
    __shared__ int    segOff[2][8];
    __shared__ int2   eBuf[2][CAP];
    __shared__ float4 xch[2][32];

    const int i = blockIdx.x;
    const int lane = threadIdx.x & 63;
    const int w = threadIdx.x >> 6;
    const int eh = lane >> 5;                          // which edge of a pair
    const int f4 = lane & 31;                          // feature quad
    const unsigned f4x4 = (unsigned)f4 * 4u;

    // --- CSR ranges in lanes 0..6; padded-to-8 exclusive scan ---
    int a = 0, len = 0;
    if (lane < 7) {
        int n = (w * 7 + lane) * NODES_PER_FRAME + i;
        a = row_ptr[n];
        len = row_ptr[n + 1] - a;
    }
    int len8 = (len + 7) & ~7;
    int off = 0;
#pragma unroll
    for (int f2 = 0; f2 < 7; ++f2) {
        int L2 = __shfl(len8, f2);
        if (f2 < lane) off += L2;
    }
    if (lane < 7) { segStart[w][lane] = a; segLen[w][lane] = len; segOff[w][lane] = off; }
    if (lane == 6) segOff[w][7] = off + len8;
    __syncthreads();

    const bool fit = segOff[w][7] <= CAP;              // wave-uniform

    // --- stage (col, val'=val*scale[col]) into LDS, zero-padded per frame ---
    if (fit) {
#pragma unroll 1
        for (int f = 0; f < 7; ++f) {
            int g = segStart[w][f], s = segOff[w][f], L = segLen[w][f];
            int L8 = (L + 7) & ~7;
            for (int j = lane; j < L8; j += 64) {
                int2 v = make_int2(0, 0);
                if (j < L) {
                    int c = edge_col[g + j];
                    v.x = c;
                    v.y = __float_as_int(edge_val[g + j] * scales[c]);
                }
                eBuf[w][s + j] = v;
            }
        }
    }
    __syncthreads();

    const float4 bb = *(const float4*)&b[f4 * 4];
    float4 mx = make_float4(0.f, 0.f, 0.f, 0.f);       // relu => max >= 0

    if (fit) {
#pragma unroll 1
        for (int f = 0; f < 7; ++f) {
            int s = segOff[w][f];
            int e8 = s + ((segLen[w][f] + 7) & ~7);
            float a0 = 0.f, a1 = 0.f, a2 = 0.f, a3 = 0.f, svf = 0.f;
            for (int j = s; j < e8; j += 8) {
                int2 ed[4];
#pragma unroll
                for (int p = 0; p < 4; ++p) ed[p] = eBuf[w][j + 2 * p + eh];
                unsigned q4[4];
#pragma unroll
                for (int p = 0; p < 4; ++p)
                    q4[p] = *(const unsigned*)(supQ + (((unsigned)ed[p].x) << 7) + f4x4);
#pragma unroll
                for (int p = 0; p < 4; ++p) {
                    float vp = __int_as_float(ed[p].y);
                    a0 = fmaf(vp, (float)( q4[p]        & 0xffu), a0);
                    a1 = fmaf(vp, (float)((q4[p] >> 8)  & 0xffu), a1);
                    a2 = fmaf(vp, (float)((q4[p] >> 16) & 0xffu), a2);
                    a3 = fmaf(vp, (float)( q4[p] >> 24        ), a3);
                    svf += vp;
                }
            }
            a0 += __shfl_xor(a0, 32); a1 += __shfl_xor(a1, 32);
            a2 += __shfl_xor(a2, 32); a3 += __shfl_xor(a3, 32);
            svf += __shfl_xor(svf, 32);
            float h0 = fmaf(-128.f, svf, a0) + bb.x;
            float h1 = fmaf(-128.f, svf, a1) + bb.y;
            float h2 = fmaf(-128.f, svf, a2) + bb.z;
            float h3 = fmaf(-128.f, svf, a3) + bb.w;
            mx.x = fmaxf(mx.x, fmaxf(h0, 0.f));
            mx.y = fmaxf(mx.y, fmaxf(h1, 0.f));
            mx.z = fmaxf(mx.z, fmaxf(h2, 0.f));
            mx.w = fmaxf(mx.w, fmaxf(h3, 0.f));
        }
    } else {
        // safety fallback: direct global reads, same math, halves split by eh
#pragma unroll 1
        for (int f = 0; f < 7; ++f) {
            int g = segStart[w][f], L = segLen[w][f];
            float a0 = 0.f, a1 = 0.f, a2 = 0.f, a3 = 0.f, svf = 0.f;
            for (int j = eh; j < L; j += 2) {
                int c = edge_col[g + j];
                float vp = edge_val[g + j] * scales[c];
                unsigned qv = *(const unsigned*)(supQ + (((unsigned)c) << 7) + f4x4);
                a0 = fmaf(vp, (float)( qv        & 0xffu), a0);
                a1 = fmaf(vp, (float)((qv >> 8)  & 0xffu), a1);
                a2 = fmaf(vp, (float)((qv >> 16) & 0xffu), a2);
                a3 = fmaf(vp, (float)( qv >> 24        ), a3);
                svf += vp;
            }
            a0 += __shfl_xor(a0, 32); a1 += __shfl_xor(a1, 32);
            a2 += __shfl_xor(a2, 32); a3 += __shfl_xor(a3, 32);
            svf += __shfl_xor(svf, 32);
            float h0 = fmaf(-128.f, svf, a0) + bb.x;
            float h1 = fmaf(-128.f, svf, a1) + bb.y;
            float h2 = fmaf(-128.f, svf, a2) + bb.z;
            float h3 = fmaf(-128.f, svf, a3) + bb.w;
            mx.x = fmaxf(mx.x, fmaxf(h0, 0.f));
            mx.y = fmaxf(mx.y, fmaxf(h1, 0.f));
            mx.z = fmaxf(mx.z, fmaxf(h2, 0.f));
            mx.w = fmaxf(mx.w, fmaxf(h3, 0.f));
        }
    }

    // --- cross-wave max exchange (halves are identical post-reduction) ---
    if (eh == 0) xch[w][f4] = mx;
    __syncthreads();
    float4 m0 = xch[0][f4], m1 = xch[1][f4];
    float o0 = fmaxf(m0.x, m1.x);
    float o1 = fmaxf(m0.y, m1.y);
    float o2 = fmaxf(m0.z, m1.z);
    float o3 = fmaxf(m0.w, m1.w);

    // --- log_softmax over 128 feats (reduce across the 32 f4 groups) ---
    float M = fmaxf(fmaxf(o0, o1), fmaxf(o2, o3));
#pragma unroll
    for (int o = 16; o >= 1; o >>= 1) M = fmaxf(M, __shfl_xor(M, o));
    float S = __expf(o0 - M) + __expf(o1 - M) + __expf(o2 - M) + __expf(o3 - M);
#pragma unroll
    for (int o = 16; o >= 1; o >>= 1) S += __shfl_xor(S, o);

    if (w == 0 && eh == 0) {
        float ls = __logf(S);
        *(float4*)&out[i * 128 + f4 * 4] =
            make_float4(o0 - M - ls, o1 - M - ls, o2 - M - ls, o3 - M - ls);
    }
}

// ---------------------------------------------------------------------------
extern "C" void kernel_launch(void* const* d_in, const int* in_sizes, int n_in,
                              void* d_out, int out_size, void* d_ws, size_t ws_size,
                              hipStream_t stream) {
    const float* x        = (const float*)d_in[0];
    const float* W        = (const float*)d_in[1];
    const float* b        = (const float*)d_in[2];
    const float* edge_val = (const float*)d_in[3];
    const int*   edge_row = (const int*)d_in[4];
    const int*   edge_col = (const int*)d_in[5];
    float* out = (float*)d_out;

    char* ws = (char*)d_ws;
    unsigned char*  supQ    = (unsigned char*)ws;                   // 17,920,000 B
    float*          scales  = (float*)(ws + 17920000);              //    560,000 B
    unsigned short* WT      = (unsigned short*)(ws + 18480000);     //     32,768 B
    int*            row_ptr = (int*)(ws + 18512768);                //    560,004 B

    prep_kernel<<<64 + EDGE_BLOCKS, 256, 0, stream>>>(W, WT, edge_row, row_ptr);
    gemm_kernel<<<GEMM_GRID, 512, 0, stream>>>(x, WT, supQ, scales);
    agg_kernel<<<NODES_PER_FRAME, 128, 0, stream>>>(supQ, scales, b, edge_val, edge_col, row_ptr, out);
}

// Round 5
// 196.066 us; speedup vs baseline: 1.2872x; 1.0046x over previous
//
#include <hip/hip_runtime.h>
#include <hip/hip_bf16.h>

#define N_NODES 140000
#define N_EDGES 2240000
#define NFEAT 128
#define NHID 128
#define N_FRAMES 14
#define NODES_PER_FRAME 10000
#define CAP 352            // int2 LDS slots per wave (7 frames padded to x8)
#define NCHUNK (CAP / 8)   // 44 chunk slots per wave

#define N_TILES 8750       // N_NODES / 16, exact
#define GEMM_GRID 512      // 512-thr blocks: 2 blocks/CU (LDS+VGPR), 16 waves/CU
#define WAVES_PER_BLOCK 8
#define WT_STRIDE 136
#define EDGE_BLOCKS ((N_EDGES + 255) / 256)

typedef __attribute__((ext_vector_type(8))) short frag_b16;
typedef __attribute__((ext_vector_type(4))) int frag_i4;
typedef __attribute__((ext_vector_type(4))) float f32x4;

__device__ __forceinline__ unsigned short f2bf(float f) {
    union { float f; unsigned int u; } v; v.f = f;
    unsigned int r = v.u + 0x7fffu + ((v.u >> 16) & 1u);   // RNE
    return (unsigned short)(r >> 16);
}
__device__ __forceinline__ int pk_bf16(float a, float b) {
    union { __hip_bfloat162 h; int i; } u;
    u.h = __float22bfloat162_rn(make_float2(a, b));        // v_cvt_pk_bf16_f32
    return u.i;
}

// ---------------------------------------------------------------------------
// Prep: blocks [0,64): W (f32) -> WT (bf16, transposed) in global.
//       blocks [64, ...): CSR row_ptr from sorted COO rows.
// ---------------------------------------------------------------------------
__global__ __launch_bounds__(256) void prep_kernel(
        const float* __restrict__ W, unsigned short* __restrict__ WT,
        const int* __restrict__ edge_row, int* __restrict__ row_ptr) {
    if (blockIdx.x < 64) {
        int e = blockIdx.x * 256 + threadIdx.x;        // 16384 = NFEAT*NHID
        int k = e >> 7, n = e & 127;
        WT[n * 128 + k] = f2bf(W[e]);
        return;
    }
    int e = (blockIdx.x - 64) * 256 + threadIdx.x;
    if (e < N_EDGES) {
        int r = edge_row[e];
        int prev = (e == 0) ? -1 : edge_row[e - 1];
        for (int q = prev + 1; q <= r; ++q) row_ptr[q] = e;
        if (e == N_EDGES - 1) {
            for (int q = r + 1; q <= N_NODES; ++q) row_ptr[q] = N_EDGES;
        }
    }
}

// ---------------------------------------------------------------------------
// GEMM: support = x @ W via mfma_f32_16x16x32_bf16, int8 row-quant epilogue.
// (verified round-4 version, unchanged)
// ---------------------------------------------------------------------------
__global__ __launch_bounds__(512) void gemm_kernel(
        const float* __restrict__ x, const unsigned short* __restrict__ WT,
        unsigned char* __restrict__ supQ, float* __restrict__ scales) {
    __shared__ unsigned short wt_lds[128 * WT_STRIDE];

    const int wave = threadIdx.x >> 6;
    const int lane = threadIdx.x & 63;
    const int m = lane & 15;
    const int q = lane >> 4;
    const bool qb0 = (q & 1);                          // q bit 0
    const bool qb1 = (q & 2);                          // q bit 1

    // --- issue first tile's x loads before WT staging (all in flight) ---
    int tile = blockIdx.x * WAVES_PER_BLOCK + wave;
    float4 pf[8];
    {
        const float* xr = x + (long)(tile * 16 + m) * 128 + q * 8;
#pragma unroll
        for (int ks = 0; ks < 4; ++ks) {
            pf[2 * ks]     = *(const float4*)(xr + ks * 32);
            pf[2 * ks + 1] = *(const float4*)(xr + ks * 32 + 4);
        }
    }

    // --- stage WT into LDS (uint4, conflict-free) ---
    const uint4* WTv = (const uint4*)WT;               // 2048 uint4
    for (int idx = threadIdx.x; idx < 2048; idx += 512) {
        uint4 d = WTv[idx];
        int elem = idx << 3;
        int n = elem >> 7, k = elem & 127;
        *(uint4*)&wt_lds[n * WT_STRIDE + k] = d;
    }
    __syncthreads();

    for (;;) {
        // convert current tile's x to bf16 fragments (pf dies here)
        frag_b16 xa[4];
#pragma unroll
        for (int ks = 0; ks < 4; ++ks) {
            union { frag_b16 f; frag_i4 i; } u;
            u.i[0] = pk_bf16(pf[2 * ks].x, pf[2 * ks].y);
            u.i[1] = pk_bf16(pf[2 * ks].z, pf[2 * ks].w);
            u.i[2] = pk_bf16(pf[2 * ks + 1].x, pf[2 * ks + 1].y);
            u.i[3] = pk_bf16(pf[2 * ks + 1].z, pf[2 * ks + 1].w);
            xa[ks] = u.f;
        }

        // prefetch next tile's x (hides under MFMA + epilogue)
        const int next = tile + GEMM_GRID * WAVES_PER_BLOCK;
        const bool more = next < N_TILES;
        if (more) {
            const float* xr = x + (long)(next * 16 + m) * 128 + q * 8;
#pragma unroll
            for (int ks = 0; ks < 4; ++ks) {
                pf[2 * ks]     = *(const float4*)(xr + ks * 32);
                pf[2 * ks + 1] = *(const float4*)(xr + ks * 32 + 4);
            }
        }

        f32x4 acc[8];
#pragma unroll
        for (int t = 0; t < 8; ++t) acc[t] = (f32x4){0.f, 0.f, 0.f, 0.f};

#pragma unroll
        for (int t = 0; t < 8; ++t) {
            const unsigned short* bp = &wt_lds[(t * 16 + m) * WT_STRIDE + q * 8];
#pragma unroll
            for (int ks = 0; ks < 4; ++ks) {
                frag_b16 wfrag = *(const frag_b16*)(bp + ks * 32);
                acc[t] = __builtin_amdgcn_mfma_f32_16x16x32_bf16(wfrag, xa[ks], acc[t], 0, 0, 0);
            }
        }

        // --- int8 row quantization epilogue ---
        float amax = 0.f;
#pragma unroll
        for (int t = 0; t < 8; ++t)
#pragma unroll
            for (int r = 0; r < 4; ++r) amax = fmaxf(amax, fabsf(acc[t][r]));
        amax = fmaxf(amax, __shfl_xor(amax, 16));
        amax = fmaxf(amax, __shfl_xor(amax, 32));
        float rinv = amax > 0.f ? 127.f / amax : 0.f;

        long node = (long)tile * 16 + m;
        if (q == 0) scales[node] = amax * (1.f / 127.f);

        // quantize+pack per half, 4x4 transpose across q-groups, store one
        // uint4 of a single row per lane -> full 64B lines per wave-store
        unsigned char* srow = supQ + node * 128;
#pragma unroll
        for (int h = 0; h < 2; ++h) {
            unsigned t4[4];
#pragma unroll
            for (int t = 0; t < 4; ++t) {
                const f32x4 av = acc[4 * h + t];
                unsigned u0 = (unsigned)(rintf(av[0] * rinv) + 128.f);
                unsigned u1 = (unsigned)(rintf(av[1] * rinv) + 128.f);
                unsigned u2 = (unsigned)(rintf(av[2] * rinv) + 128.f);
                unsigned u3 = (unsigned)(rintf(av[3] * rinv) + 128.f);
                t4[t] = u0 | (u1 << 8) | (u2 << 16) | (u3 << 24);
            }
            unsigned g1 = __shfl_xor(qb0 ? t4[0] : t4[1], 16);
            unsigned g2 = __shfl_xor(qb0 ? t4[2] : t4[3], 16);
            unsigned c0 = qb0 ? g1 : t4[0];
            unsigned c1 = qb0 ? t4[1] : g1;
            unsigned c2 = qb0 ? g2 : t4[2];
            unsigned c3 = qb0 ? t4[3] : g2;
            unsigned g3 = __shfl_xor(qb1 ? c0 : c2, 32);
            unsigned g4 = __shfl_xor(qb1 ? c1 : c3, 32);
            uint4 o;
            o.x = qb1 ? g3 : c0;
            o.y = qb1 ? g4 : c1;
            o.z = qb1 ? c2 : g3;
            o.w = qb1 ? c3 : g4;
            *(uint4*)(srow + h * 64 + q * 16) = o;
        }

        if (!more) break;
        tile = next;
    }
}

// ---------------------------------------------------------------------------
// Fused aggregation v4: flat chunk stream + 2-deep software pipeline.
// Block = 128 thr = 2 waves = 1 output node. Wave w: frames [7w, 7w+6].
// All 7 frame segments are contiguous and 8-aligned in eBuf -> iterate one
// flat chunk loop with a per-chunk frame-id table; next chunk's LDS reads +
// global gathers stay in flight across the (wave-uniform) frame flushes.
// Same per-frame accumulation order -> bit-identical to v3.
// ---------------------------------------------------------------------------
__global__ __launch_bounds__(128) void agg_kernel(
        const unsigned char* __restrict__ supQ, const float* __restrict__ scales,
        const float* __restrict__ b,
        const float* __restrict__ edge_val, const int* __restrict__ edge_col,
        const int* __restrict__ row_ptr, float* __restrict__ out) {
    __shared__ int    segStart[2][8];
    __shared__ int    segLen[2][8];
    __shared__ int    segOff[2][8];
    __shared__ int2   eBuf[2][CAP];
    __shared__ unsigned char fidBuf[2][NCHUNK];
    __shared__ float4 xch[2][32];

    const int i = blockIdx.x;
    const int lane = threadIdx.x & 63;
    const int w = threadIdx.x >> 6;
    const int eh = lane >> 5;                          // which edge of a pair
    const int f4 = lane & 31;                          // feature quad
    const unsigned f4x4 = (unsigned)f4 * 4u;

    // --- CSR ranges in lanes 0..6; padded-to-8 exclusive scan ---
    int a = 0, len = 0;
    if (lane < 7) {
        int n = (w * 7 + lane) * NODES_PER_FRAME + i;
        a = row_ptr[n];
        len = row_ptr[n + 1] - a;
    }
    int len8 = (len + 7) & ~7;
    int off = 0;
#pragma unroll
    for (int f2 = 0; f2 < 7; ++f2) {
        int L2 = __shfl(len8, f2);
        if (f2 < lane) off += L2;
    }
    if (lane < 7) { segStart[w][lane] = a; segLen[w][lane] = len; segOff[w][lane] = off; }
    if (lane == 6) segOff[w][7] = off + len8;
    // per-chunk frame ids (chunks of this frame: [off/8, (off+len8)/8) )
    if (lane < 7) {
        for (int c = off >> 3, ce = (off + len8) >> 3; c < ce && c < NCHUNK; ++c)
            fidBuf[w][c] = (unsigned char)lane;
    }
    const bool anyEmpty = (__ballot(lane < 7 && len == 0) & 0x7full) != 0;
    __syncthreads();

    const bool fit = segOff[w][7] <= CAP;              // wave-uniform

    // --- stage (col, val'=val*scale[col]) into LDS, zero-padded per frame ---
    if (fit) {
#pragma unroll 1
        for (int f = 0; f < 7; ++f) {
            int g = segStart[w][f], s = segOff[w][f], L = segLen[w][f];
            int L8 = (L + 7) & ~7;
            for (int j = lane; j < L8; j += 64) {
                int2 v = make_int2(0, 0);
                if (j < L) {
                    int c = edge_col[g + j];
                    v.x = c;
                    v.y = __float_as_int(edge_val[g + j] * scales[c]);
                }
                eBuf[w][s + j] = v;
            }
        }
    }
    __syncthreads();

    const float4 bb = *(const float4*)&b[f4 * 4];
    float4 mx = make_float4(0.f, 0.f, 0.f, 0.f);       // relu => max >= 0

    if (fit) {
        const int total = segOff[w][7];
        float a0 = 0.f, a1 = 0.f, a2 = 0.f, a3 = 0.f, svf = 0.f;
        if (total > 0) {
            int curf = fidBuf[w][0];
            // prologue: chunk 0
            int2 ed[4]; unsigned q4[4];
#pragma unroll
            for (int p = 0; p < 4; ++p) ed[p] = eBuf[w][2 * p + eh];
#pragma unroll
            for (int p = 0; p < 4; ++p)
                q4[p] = *(const unsigned*)(supQ + (((unsigned)ed[p].x) << 7) + f4x4);

            for (int j = 0; ; ) {
                const int jn = j + 8;
                const bool more = jn < total;
                int2 ed2[4]; unsigned q42[4];
                if (more) {                            // issue next chunk early
#pragma unroll
                    for (int p = 0; p < 4; ++p) ed2[p] = eBuf[w][jn + 2 * p + eh];
#pragma unroll
                    for (int p = 0; p < 4; ++p)
                        q42[p] = *(const unsigned*)(supQ + (((unsigned)ed2[p].x) << 7) + f4x4);
                }
                const int f = fidBuf[w][j >> 3];       // wave-uniform
                if (f != curf) {
                    // flush frame curf (gathers for chunk jn stay in flight)
                    a0 += __shfl_xor(a0, 32); a1 += __shfl_xor(a1, 32);
                    a2 += __shfl_xor(a2, 32); a3 += __shfl_xor(a3, 32);
                    svf += __shfl_xor(svf, 32);
                    float h0 = fmaf(-128.f, svf, a0) + bb.x;
                    float h1 = fmaf(-128.f, svf, a1) + bb.y;
                    float h2 = fmaf(-128.f, svf, a2) + bb.z;
                    float h3 = fmaf(-128.f, svf, a3) + bb.w;
                    mx.x = fmaxf(mx.x, fmaxf(h0, 0.f));
                    mx.y = fmaxf(mx.y, fmaxf(h1, 0.f));
                    mx.z = fmaxf(mx.z, fmaxf(h2, 0.f));
                    mx.w = fmaxf(mx.w, fmaxf(h3, 0.f));
                    a0 = a1 = a2 = a3 = svf = 0.f;
                    curf = f;
                }
#pragma unroll
                for (int p = 0; p < 4; ++p) {
                    float vp = __int_as_float(ed[p].y);
                    a0 = fmaf(vp, (float)( q4[p]        & 0xffu), a0);
                    a1 = fmaf(vp, (float)((q4[p] >> 8)  & 0xffu), a1);
                    a2 = fmaf(vp, (float)((q4[p] >> 16) & 0xffu), a2);
                    a3 = fmaf(vp, (float)( q4[p] >> 24        ), a3);
                    svf += vp;
                }
                if (!more) break;
#pragma unroll
                for (int p = 0; p < 4; ++p) { ed[p] = ed2[p]; q4[p] = q42[p]; }
                j = jn;
            }
            // final flush
            a0 += __shfl_xor(a0, 32); a1 += __shfl_xor(a1, 32);
            a2 += __shfl_xor(a2, 32); a3 += __shfl_xor(a3, 32);
            svf += __shfl_xor(svf, 32);
            float h0 = fmaf(-128.f, svf, a0) + bb.x;
            float h1 = fmaf(-128.f, svf, a1) + bb.y;
            float h2 = fmaf(-128.f, svf, a2) + bb.z;
            float h3 = fmaf(-128.f, svf, a3) + bb.w;
            mx.x = fmaxf(mx.x, fmaxf(h0, 0.f));
            mx.y = fmaxf(mx.y, fmaxf(h1, 0.f));
            mx.z = fmaxf(mx.z, fmaxf(h2, 0.f));
            mx.w = fmaxf(mx.w, fmaxf(h3, 0.f));
        }
        if (anyEmpty) {
            // empty frame: agg=0, svf=0 -> h = b exactly (max is idempotent)
            mx.x = fmaxf(mx.x, fmaxf(bb.x, 0.f));
            mx.y = fmaxf(mx.y, fmaxf(bb.y, 0.f));
            mx.z = fmaxf(mx.z, fmaxf(bb.z, 0.f));
            mx.w = fmaxf(mx.w, fmaxf(bb.w, 0.f));
        }
    } else {
        // safety fallback: direct global reads, same math, halves split by eh
#pragma unroll 1
        for (int f = 0; f < 7; ++f) {
            int g = segStart[w][f], L = segLen[w][f];
            float a0 = 0.f, a1 = 0.f, a2 = 0.f, a3 = 0.f, svf = 0.f;
            for (int j = eh; j < L; j += 2) {
                int c = edge_col[g + j];
                float vp = edge_val[g + j] * scales[c];
                unsigned qv = *(const unsigned*)(supQ + (((unsigned)c) << 7) + f4x4);
                a0 = fmaf(vp, (float)( qv        & 0xffu), a0);
                a1 = fmaf(vp, (float)((qv >> 8)  & 0xffu), a1);
                a2 = fmaf(vp, (float)((qv >> 16) & 0xffu), a2);
                a3 = fmaf(vp, (float)( qv >> 24        ), a3);
                svf += vp;
            }
            a0 += __shfl_xor(a0, 32); a1 += __shfl_xor(a1, 32);
            a2 += __shfl_xor(a2, 32); a3 += __shfl_xor(a3, 32);
            svf += __shfl_xor(svf, 32);
            float h0 = fmaf(-128.f, svf, a0) + bb.x;
            float h1 = fmaf(-128.f, svf, a1) + bb.y;
            float h2 = fmaf(-128.f, svf, a2) + bb.z;
            float h3 = fmaf(-128.f, svf, a3) + bb.w;
            mx.x = fmaxf(mx.x, fmaxf(h0, 0.f));
            mx.y = fmaxf(mx.y, fmaxf(h1, 0.f));
            mx.z = fmaxf(mx.z, fmaxf(h2, 0.f));
            mx.w = fmaxf(mx.w, fmaxf(h3, 0.f));
        }
    }

    // --- cross-wave max exchange (halves are identical post-reduction) ---
    if (eh == 0) xch[w][f4] = mx;
    __syncthreads();
    float4 m0 = xch[0][f4], m1 = xch[1][f4];
    float o0 = fmaxf(m0.x, m1.x);
    float o1 = fmaxf(m0.y, m1.y);
    float o2 = fmaxf(m0.z, m1.z);
    float o3 = fmaxf(m0.w, m1.w);

    // --- log_softmax over 128 feats (reduce across the 32 f4 groups) ---
    float M = fmaxf(fmaxf(o0, o1), fmaxf(o2, o3));
#pragma unroll
    for (int o = 16; o >= 1; o >>= 1) M = fmaxf(M, __shfl_xor(M, o));
    float S = __expf(o0 - M) + __expf(o1 - M) + __expf(o2 - M) + __expf(o3 - M);
#pragma unroll
    for (int o = 16; o >= 1; o >>= 1) S += __shfl_xor(S, o);

    if (w == 0 && eh == 0) {
        float ls = __logf(S);
        *(float4*)&out[i * 128 + f4 * 4] =
            make_float4(o0 - M - ls, o1 - M - ls, o2 - M - ls, o3 - M - ls);
    }
}

// ---------------------------------------------------------------------------
extern "C" void kernel_launch(void* const* d_in, const int* in_sizes, int n_in,
                              void* d_out, int out_size, void* d_ws, size_t ws_size,
                              hipStream_t stream) {
    const float* x        = (const float*)d_in[0];
    const float* W        = (const float*)d_in[1];
    const float* b        = (const float*)d_in[2];
    const float* edge_val = (const float*)d_in[3];
    const int*   edge_row = (const int*)d_in[4];
    const int*   edge_col = (const int*)d_in[5];
    float* out = (float*)d_out;

    char* ws = (char*)d_ws;
    unsigned char*  supQ    = (unsigned char*)ws;                   // 17,920,000 B
    float*          scales  = (float*)(ws + 17920000);              //    560,000 B
    unsigned short* WT      = (unsigned short*)(ws + 18480000);     //     32,768 B
    int*            row_ptr = (int*)(ws + 18512768);                //    560,004 B

    prep_kernel<<<64 + EDGE_BLOCKS, 256, 0, stream>>>(W, WT, edge_row, row_ptr);
    gemm_kernel<<<GEMM_GRID, 512, 0, stream>>>(x, WT, supQ, scales);
    agg_kernel<<<NODES_PER_FRAME, 128, 0, stream>>>(supQ, scales, b, edge_val, edge_col, row_ptr, out);
}